// Round 12
// baseline (26.231 us; speedup 1.0000x reference)
//
#include <hip/hip_runtime.h>

// 3x3 cross-correlation, padding=1, NCHW, fp32 in/out, bf16 MFMA compute.
// out[b,o,h,w] = bias[o] + sum_{i,c} comb[o, i*16+c] * x[b,c,h+dy_i,w+dx_i]
// B=4, C=16, O=16, H=450, W=480. K = 144 = 9 flows x 16 c, padded to 5x32.
//
// Round 12: operand swap for wide stores. R8 geometry (best: 25.0us, block
// scan minimum at 3/CU). MFMA A/B frags are lane-symmetric (lane&15 =
// non-K index, k=(lane>>4)*8+j), so mfma(x_frag, w_frag, acc) instead of
// mfma(w_frag, x_frag, acc) flips D to row=pixel, col=o: each lane holds
// 4 CONSECUTIVE pixels of one o-plane -> one float4 store per tile
// (was 4 scalar dword stores to 4 different planes). 216k -> 54k wave
// stores, 1/4 store-address VALU. LDS reads/frag construction unchanged.

#define HH 450
#define WW 480
#define BB 4
#define CC 16
#define OO 16
#define WT    96                 // output pixels per block (width), 6 tiles
#define WQN   5                  // width groups
#define WIN   104                // staged wi count (w0-4 .. w0+99)
#define RSTG  14                 // staged rows per block
#define ROUT  12                 // output rows per block
#define HG    38                 // row-groups: ceil(450/12)
#define NTILE 6                  // 16-pixel MFMA tiles per row
#define W4N   26                 // float4 groups per staged row
#define HALF  (RSTG * W4N)       // 364 items per c-half
#define ITEMS (2 * HALF)         // 728 staging items
#define PLANE (RSTG * WIN)       // 1456 LDS rows per c-half
#define NBLK  (BB * WQN * HG)    // 760 = 8 * 95

typedef __attribute__((ext_vector_type(8))) short    bf16x8;
typedef __attribute__((ext_vector_type(4))) float    f32x4;
typedef __attribute__((ext_vector_type(4))) unsigned u32x4;

static __device__ __forceinline__ unsigned cvt_pk_bf16(float a, float b) {
    unsigned r;
    asm("v_cvt_pk_bf16_f32 %0, %1, %2" : "=v"(r) : "v"(a), "v"(b));
    return r;   // lo16 = bf16(a), hi16 = bf16(b), RNE
}

__global__ __launch_bounds__(256, 3) void flow_mfma_kernel(
    const float* __restrict__ x, const float* __restrict__ comb,
    const float* __restrict__ bias, float* __restrict__ out)
{
    // flat [2 c-half planes x 14 rows x 104 wi][8 shorts] : 46592 B
    __shared__ __align__(16) short xs[2 * PLANE][8];

    const int tid  = threadIdx.x;
    const int lane = tid & 63;
    const int wv   = tid >> 6;

    // ---- bijective XCD swizzle: 760 = 8*95 exactly ----
    int bid = blockIdx.x;
    int L   = (bid & 7) * 95 + (bid >> 3);
    // decode: L = (b*WQN + wq)*HG + hg  (hg fastest -> vertical L2 strips)
    int hg  = L % HG;
    int t2  = L / HG;
    int wq  = t2 % WQN;
    int b   = t2 / WQN;
    int h0  = hg * ROUT;
    int w0  = wq * WT;

    // ---- weight frags (B operand): fp32->bf16 once, in VGPRs ----
    const int col = lane & 15;          // o (B col) / pixel-in-tile (A row)
    const int grp = lane >> 4;          // 0..3
    bf16x8 wf[5];
    #pragma unroll
    for (int m = 0; m < 5; ++m) {
        int k0 = m * 32 + grp * 8;
        u32x4 p;
        if (k0 < 144) {
            float4 u = *(const float4*)(comb + col * 144 + k0);
            float4 v = *(const float4*)(comb + col * 144 + k0 + 4);
            p[0] = cvt_pk_bf16(u.x, u.y);
            p[1] = cvt_pk_bf16(u.z, u.w);
            p[2] = cvt_pk_bf16(v.x, v.y);
            p[3] = cvt_pk_bf16(v.z, v.w);
        } else {
            p[0] = p[1] = p[2] = p[3] = 0u;
        }
        wf[m] = __builtin_bit_cast(bf16x8, p);
    }
    // acc init: D[pixel][o], col = o -> all 4 regs = bias[col]
    float bcol = bias[col];
    f32x4 bv = { bcol, bcol, bcol, bcol };

    // ---- stage x -> LDS bf16 (float4 items: 8 planes x 4 pixels) ----
    auto stage = [&](int s) {
        int cs  = (s >= HALF) ? 1 : 0;
        int rem = s - cs * HALF;
        int r   = rem / W4N;              // 0..13
        int wi4 = rem - r * W4N;          // 0..25
        int hy  = h0 - 1 + r;
        int w   = w0 - 4 + wi4 * 4;
        u32x4 p[4];
        if (((unsigned)hy < (unsigned)HH) && ((unsigned)w < (unsigned)WW)) {
            const float* xp = x + (((size_t)(b * CC + cs * 8) * HH + hy) * WW + w);
            float4 v[8];
            #pragma unroll
            for (int j = 0; j < 8; ++j)
                v[j] = *(const float4*)(xp + (size_t)j * HH * WW);
            #pragma unroll
            for (int q = 0; q < 4; ++q) {
                p[0][q] = cvt_pk_bf16(v[2*q].x, v[2*q+1].x);
                p[1][q] = cvt_pk_bf16(v[2*q].y, v[2*q+1].y);
                p[2][q] = cvt_pk_bf16(v[2*q].z, v[2*q+1].z);
                p[3][q] = cvt_pk_bf16(v[2*q].w, v[2*q+1].w);
            }
        } else {
            #pragma unroll
            for (int k = 0; k < 4; ++k)
                p[k][0] = p[k][1] = p[k][2] = p[k][3] = 0u;
        }
        int r2 = cs * PLANE + r * WIN + wi4 * 4;
        #pragma unroll
        for (int k = 0; k < 4; ++k)
            *(u32x4*)(&xs[r2 + k][0]) = p[k];
    };
    #pragma unroll
    for (int it = 0; it < 2; ++it)        // 512 items
        stage(tid + it * 256);
    if (tid < ITEMS - 2 * 256)            // tail: 216 items
        stage(tid + 2 * 256);
    __syncthreads();

    // ---- per-lane x-frag (A operand) column offsets ----
    // A[m=pixel=col][k=grp*8+j]: chunk m<4 -> flow i=2m+(grp>>1), ch=grp&1
    const int fo = grp >> 1;
    const int ch = grp & 1;
    int cof[5];
    #pragma unroll
    for (int m = 0; m < 4; ++m) {
        int i  = 2 * m + fo;
        int ky = i / 3;
        int kx = i - ky * 3;
        cof[m] = ch * PLANE + ky * WIN + col + kx + 3;
    }
    cof[4] = ch * PLANE + 2 * WIN + col + 5;   // flow 8 (ky=2, kx=2)

    // ---- compute: 72 tiles round-robin over 4 waves (18 each) ----
    #pragma unroll
    for (int k = 0; k < 18; ++k) {
        int idx = wv + 4 * k;             // 0..71
        int row = idx / 6;                // 0..11
        int t   = idx - row * 6;          // 0..5
        int h   = h0 + row;
        if (h >= HH) continue;
        int n0  = t * 16;
        int rbase = row * WIN + n0;
        f32x4 acc = bv;
        #pragma unroll
        for (int m = 0; m < 4; ++m) {
            bf16x8 xf = *(const bf16x8*)(&xs[rbase + cof[m]][0]);
            acc = __builtin_amdgcn_mfma_f32_16x16x32_bf16(xf, wf[m], acc, 0, 0, 0);
        }
        bf16x8 x4;
        if (grp < 2) {
            x4 = *(const bf16x8*)(&xs[rbase + cof[4]][0]);
        } else {
            #pragma unroll
            for (int j = 0; j < 8; ++j) x4[j] = 0;
        }
        acc = __builtin_amdgcn_mfma_f32_16x16x32_bf16(x4, wf[4], acc, 0, 0, 0);

        // D: row = pixel = grp*4 + r, col = o -> lane stores 4 consecutive
        // pixels of plane o=col as one float4
        float* op = out + (((size_t)(b * OO + col) * HH + h) * WW
                           + w0 + n0 + grp * 4);
        *(f32x4*)op = acc;
    }
}

extern "C" void kernel_launch(void* const* d_in, const int* in_sizes, int n_in,
                              void* d_out, int out_size, void* d_ws, size_t ws_size,
                              hipStream_t stream) {
    const float* x    = (const float*)d_in[0];
    const float* comb = (const float*)d_in[1];
    const float* bias = (const float*)d_in[2];
    float* out        = (float*)d_out;

    flow_mfma_kernel<<<NBLK, 256, 0, stream>>>(x, comb, bias, out);
}

// Round 13
// 25.052 us; speedup vs baseline: 1.0471x; 1.0471x over previous
//
#include <hip/hip_runtime.h>

// 3x3 cross-correlation, padding=1, NCHW, fp32 in/out, bf16 MFMA compute.
// out[b,o,h,w] = bias[o] + sum_{i,c} comb[o, i*16+c] * x[b,c,h+dy_i,w+dx_i]
// B=4, C=16, O=16, H=450, W=480. K = 144 = 9 flows x 16 c, padded to 5x32.
//
// FINAL (= Round 8, session best: 25.0us). Session ladder: 70 (fp32 VALU)
// -> 44.9 (MFMA+LDS) -> 43.4 (cvt_pk, conflict-free LDS) -> 33.3 (4-row
// blocks, halo 1.5x) -> 26.4 (balanced resident grid) -> 25.0 (this: 760 =
// 8*95 blocks, 3/CU, ROUT=12/RSTG=14, float2 staging). Explored and
// rejected: manual pipelines (R7 +5us, R9 +1.5us), 6/CU and 2/CU blocks
// (both ~+1.4us), operand-swap wide stores (+1.2us). All throughput pipes
// idle at 25us (VALU<20%, MFMA 3.5%, HBM 30%) -> latency/ramp structure;
// traffic floor ~13us.

#define HH 450
#define WW 480
#define BB 4
#define CC 16
#define OO 16
#define WT    96                 // output pixels per block (width), 6 tiles
#define WQN   5                  // width groups
#define WIN   104                // staged wi count (w0-4 .. w0+99)
#define RSTG  14                 // staged rows per block
#define ROUT  12                 // output rows per block
#define HG    38                 // row-groups: ceil(450/12)
#define NTILE 6                  // 16-pixel MFMA tiles per row
#define W2N   (WIN / 2)          // 52 float2 groups per staged row
#define HALFI (RSTG * W2N)       // 728 items per c-half
#define ITEMS (2 * HALFI)        // 1456 staging items
#define NBLK  (BB * WQN * HG)    // 760 = 8 * 95

typedef __attribute__((ext_vector_type(8))) short    bf16x8;
typedef __attribute__((ext_vector_type(4))) float    f32x4;
typedef __attribute__((ext_vector_type(4))) unsigned u32x4;

static __device__ __forceinline__ unsigned cvt_pk_bf16(float a, float b) {
    unsigned r;
    asm("v_cvt_pk_bf16_f32 %0, %1, %2" : "=v"(r) : "v"(a), "v"(b));
    return r;   // lo16 = bf16(a), hi16 = bf16(b), RNE
}

__global__ __launch_bounds__(256, 3) void flow_mfma_kernel(
    const float* __restrict__ x, const float* __restrict__ comb,
    const float* __restrict__ bias, float* __restrict__ out)
{
    // [c-half][r*WIN + wi][8 shorts] : 16B rows, 46592 B -> 3 blocks/CU
    __shared__ __align__(16) short xs[2][RSTG * WIN][8];

    const int tid  = threadIdx.x;
    const int lane = tid & 63;
    const int wv   = tid >> 6;

    // ---- bijective XCD swizzle: 760 = 8*95 exactly ----
    int bid = blockIdx.x;
    int L   = (bid & 7) * 95 + (bid >> 3);
    // decode: L = (b*WQN + wq)*HG + hg  (hg fastest -> vertical L2 strips)
    int hg  = L % HG;
    int t2  = L / HG;
    int wq  = t2 % WQN;
    int b   = t2 / WQN;
    int h0  = hg * ROUT;
    int w0  = wq * WT;

    // ---- A-frags: weights fp32->bf16 once, in VGPRs ----
    const int col = lane & 15;          // pixel-in-tile (B col) / output o (A row)
    const int grp = lane >> 4;          // 0..3
    bf16x8 af[5];
    #pragma unroll
    for (int m = 0; m < 5; ++m) {
        int k0 = m * 32 + grp * 8;
        u32x4 p;
        if (k0 < 144) {
            float4 u = *(const float4*)(comb + col * 144 + k0);
            float4 v = *(const float4*)(comb + col * 144 + k0 + 4);
            p[0] = cvt_pk_bf16(u.x, u.y);
            p[1] = cvt_pk_bf16(u.z, u.w);
            p[2] = cvt_pk_bf16(v.x, v.y);
            p[3] = cvt_pk_bf16(v.z, v.w);
        } else {
            p[0] = p[1] = p[2] = p[3] = 0u;
        }
        af[m] = __builtin_bit_cast(bf16x8, p);
    }
    f32x4 bv = *(const f32x4*)(bias + grp * 4);   // acc init: bias[grp*4+r]

    // ---- stage x -> LDS bf16 ----
    // item s: ch = s >= HALFI; rem = r*W2N + wi2; covers w = w0-4+2*wi2, +1
    auto stage = [&](int s) {
        int ch  = (s >= HALFI) ? 1 : 0;
        int rem = s - ch * HALFI;
        int r   = rem / W2N;
        int wi2 = rem - r * W2N;
        int hy  = h0 - 1 + r;
        int w   = w0 - 4 + wi2 * 2;
        u32x4 p0, p1;
        if (((unsigned)hy < (unsigned)HH) && ((unsigned)w < (unsigned)WW)) {
            const float* xp = x + (((size_t)(b * CC + ch * 8) * HH + hy) * WW + w);
            float fx[8], fy[8];
            #pragma unroll
            for (int j = 0; j < 8; ++j) {
                float2 v = *(const float2*)(xp + (size_t)j * HH * WW);
                fx[j] = v.x; fy[j] = v.y;
            }
            p0[0] = cvt_pk_bf16(fx[0], fx[1]);
            p0[1] = cvt_pk_bf16(fx[2], fx[3]);
            p0[2] = cvt_pk_bf16(fx[4], fx[5]);
            p0[3] = cvt_pk_bf16(fx[6], fx[7]);
            p1[0] = cvt_pk_bf16(fy[0], fy[1]);
            p1[1] = cvt_pk_bf16(fy[2], fy[3]);
            p1[2] = cvt_pk_bf16(fy[4], fy[5]);
            p1[3] = cvt_pk_bf16(fy[6], fy[7]);
        } else {
            p0[0] = p0[1] = p0[2] = p0[3] = 0u;
            p1[0] = p1[1] = p1[2] = p1[3] = 0u;
        }
        int r2 = r * WIN + wi2 * 2;
        *(u32x4*)(&xs[ch][r2][0])     = p0;
        *(u32x4*)(&xs[ch][r2 + 1][0]) = p1;
    };
    #pragma unroll
    for (int it = 0; it < 5; ++it)        // 5*256 = 1280 items
        stage(tid + it * 256);
    if (tid < ITEMS - 5 * 256)            // tail: 176 items
        stage(tid + 5 * 256);
    __syncthreads();

    // ---- compute: wave wv owns output rows h0 + 3wv .. h0 + 3wv + 2 ----
    const int fo = grp >> 1;
    const int ch = grp & 1;
    #pragma unroll
    for (int rr = 0; rr < 3; ++rr) {
        int r = 3 * wv + rr;              // row within group
        int h = h0 + r;
        if (h >= HH) continue;

        // pixel w0+n0+col+kx-1 -> staged wi = n0+col+kx+3
        int boff[5];
        #pragma unroll
        for (int m = 0; m < 4; ++m) {
            int i  = 2 * m + fo;
            int ky = i / 3;
            int kx = i % 3;
            boff[m] = (r + ky) * WIN + col + kx + 3;
        }
        boff[4] = (r + 2) * WIN + col + 2 + 3;   // flow 8 (ky=2, kx=2)

        #pragma unroll
        for (int t = 0; t < NTILE; ++t) {
            int n0 = t * 16;
            f32x4 acc = bv;
            #pragma unroll
            for (int m = 0; m < 4; ++m) {
                bf16x8 bf = *(const bf16x8*)(&xs[ch][boff[m] + n0][0]);
                acc = __builtin_amdgcn_mfma_f32_16x16x32_bf16(af[m], bf, acc, 0, 0, 0);
            }
            bf16x8 b4;
            if (grp < 2) {
                b4 = *(const bf16x8*)(&xs[ch][boff[4] + n0][0]);
            } else {
                #pragma unroll
                for (int j = 0; j < 8; ++j) b4[j] = 0;
            }
            acc = __builtin_amdgcn_mfma_f32_16x16x32_bf16(af[4], b4, acc, 0, 0, 0);

            // D: col = pixel, row o = grp*4 + j
            float* op = out + (((size_t)(b * OO + grp * 4) * HH + h) * WW + w0 + n0 + col);
            #pragma unroll
            for (int j = 0; j < 4; ++j)
                op[(size_t)j * HH * WW] = acc[j];
        }
    }
}

extern "C" void kernel_launch(void* const* d_in, const int* in_sizes, int n_in,
                              void* d_out, int out_size, void* d_ws, size_t ws_size,
                              hipStream_t stream) {
    const float* x    = (const float*)d_in[0];
    const float* comb = (const float*)d_in[1];
    const float* bias = (const float*)d_in[2];
    float* out        = (float*)d_out;

    flow_mfma_kernel<<<NBLK, 256, 0, stream>>>(x, comb, bias, out);
}